// Round 6
// baseline (183.377 us; speedup 1.0000x reference)
//
#include <hip/hip_runtime.h>
#include <math.h>

// Problem constants
#define BS 4
#define LQ 1024
#define EMB 256
#define NH 8
#define NL 4
#define NP 16
#define HD 32
#define LV 5440   // 64*64 + 32*32 + 16*16 + 8*8
#define KDIM 256  // all GEMMs have K = 256

typedef __attribute__((ext_vector_type(8))) short short8;  // 8 bf16 = 4 VGPRs
typedef __attribute__((ext_vector_type(4))) float f32x4;

__device__ inline unsigned short f2bf(float f) {
    unsigned u = __builtin_bit_cast(unsigned, f);
    u += 0x7fff + ((u >> 16) & 1);   // round-to-nearest-even
    return (unsigned short)(u >> 16);
}

// ---------------- prep: weight transpose+convert  AND  value/query fp32->bf16 ----
// blocks 0..511: Wt_all[2048][256] bf16 from the four [K=256][N] fp32 weights.
//   col map: 0..255 W_value | 256..1279 W_off | 1280..1791 W_attn | 1792..2047 W_out
// blocks 512..3743: elementwise cvt, 8 floats/thread: value (696320 grp), query (131072 grp).
__global__ __launch_bounds__(256) void prep(const float* __restrict__ Wv,
                                            const float* __restrict__ Wo,
                                            const float* __restrict__ Wa,
                                            const float* __restrict__ Wu,
                                            const float* __restrict__ value,
                                            const float* __restrict__ query,
                                            unsigned short* __restrict__ Wt,
                                            unsigned short* __restrict__ val_bf,
                                            unsigned short* __restrict__ qry_bf) {
    const int blk = blockIdx.x;
    if (blk < 512) {
        __shared__ float tile[32][33];
        const int n0 = (blk & 63) * 32, k0 = (blk >> 6) * 32;
        const float* src; int N, nloc;
        if (n0 < 256)       { src = Wv; N = 256;  nloc = n0; }
        else if (n0 < 1280) { src = Wo; N = 1024; nloc = n0 - 256; }
        else if (n0 < 1792) { src = Wa; N = 512;  nloc = n0 - 1280; }
        else                { src = Wu; N = 256;  nloc = n0 - 1792; }
        const int tx = threadIdx.x & 31, ty = threadIdx.x >> 5;  // ty 0..7
#pragma unroll
        for (int i = 0; i < 32; i += 8)
            tile[ty + i][tx] = src[(size_t)(k0 + ty + i) * N + nloc + tx];
        __syncthreads();
#pragma unroll
        for (int i = 0; i < 32; i += 8)
            Wt[(size_t)(n0 + ty + i) * KDIM + k0 + tx] = f2bf(tile[tx][ty + i]);
    } else {
        const int i = (blk - 512) * 256 + threadIdx.x;   // 8-float group index
        const float* src;
        unsigned short* dst;
        size_t off;
        if (i < 696320) { src = value; dst = val_bf; off = (size_t)i * 8; }
        else            { src = query; dst = qry_bf; off = (size_t)(i - 696320) * 8; }
        const float4 f0 = *(const float4*)(src + off);
        const float4 f1 = *(const float4*)(src + off + 4);
        short8 h;
        h[0] = (short)f2bf(f0.x); h[1] = (short)f2bf(f0.y);
        h[2] = (short)f2bf(f0.z); h[3] = (short)f2bf(f0.w);
        h[4] = (short)f2bf(f1.x); h[5] = (short)f2bf(f1.y);
        h[6] = (short)f2bf(f1.z); h[7] = (short)f2bf(f1.w);
        *(short8*)(dst + off) = h;
    }
}

// ---------------- barrier-free no-LDS bf16 MFMA GEMM, 128x128 tile ---------------
// 4 waves in 2x2; each wave computes 64x64 via 4x4 frags of 16x16x32.
// Both operands row-major [*][256] bf16: each fragment is one
// global_load_dwordx4 at row*512B + quad*16 + kt*64 — 16 cache lines per
// instruction, every byte consumed by the 4 quads sharing the line. No LDS,
// no __syncthreads, no vmcnt(0) drains (R5 lesson: 8-iter K-loop made the
// m97 barrier structure pure exposed latency, MfmaUtil 3%).
// MODE 0: fp32 C = acc + bias[c]
// MODE 1: fused qkv epilogue (N=1536): cols <1024 -> sampling locations with
//         reference-point polynomial; cols >=1024 -> attn logits with fused
//         softmax over each (row, head)'s 64 logits -> fp32 C2.
// MODE 2: bf16 C = f2bf(acc + bias[c])
template <int MODE>
__device__ __forceinline__ void gemm_nolds(const unsigned short* __restrict__ A,
                                           const unsigned short* __restrict__ Bt,
                                           const float* __restrict__ bias,
                                           const float* __restrict__ bias2,
                                           const float* __restrict__ refp,
                                           void* __restrict__ Cv,
                                           float* __restrict__ C2,
                                           int N, int bx, int by) {
    const int t = threadIdx.x;
    const int lane = t & 63, w = t >> 6;
    const int quad = lane >> 4, l16 = lane & 15;
    const int wr = w >> 1, wc = w & 1;
    const int row0 = by * 128, col0 = bx * 128;

    const unsigned short* ap = A  + (size_t)(row0 + wr * 64 + l16) * KDIM + quad * 8;
    const unsigned short* bp = Bt + (size_t)(col0 + wc * 64 + l16) * KDIM + quad * 8;

    f32x4 acc[4][4] = {};

#pragma unroll 2
    for (int kt = 0; kt < 8; ++kt) {
        short8 af[4], bf[4];
#pragma unroll
        for (int mi = 0; mi < 4; ++mi)
            af[mi] = *(const short8*)(ap + (size_t)mi * 16 * KDIM + kt * 32);
#pragma unroll
        for (int ni = 0; ni < 4; ++ni)
            bf[ni] = *(const short8*)(bp + (size_t)ni * 16 * KDIM + kt * 32);
#pragma unroll
        for (int mi = 0; mi < 4; ++mi)
#pragma unroll
            for (int ni = 0; ni < 4; ++ni)
                acc[mi][ni] = __builtin_amdgcn_mfma_f32_16x16x32_bf16(af[mi], bf[ni],
                                                                      acc[mi][ni], 0, 0, 0);
    }

    // C/D layout: col = lane&15, row = quad*4 + reg  [m89-verified, R2-R5 verified]
    if (MODE == 0 || MODE == 2) {
#pragma unroll
        for (int ni = 0; ni < 4; ++ni) {
            const int c = col0 + wc * 64 + ni * 16 + l16;
            const float bv = bias[c];
#pragma unroll
            for (int mi = 0; mi < 4; ++mi) {
                const int r0 = row0 + wr * 64 + mi * 16 + quad * 4;
#pragma unroll
                for (int rr = 0; rr < 4; ++rr) {
                    const float o = acc[mi][ni][rr] + bv;
                    if (MODE == 0) ((float*)Cv)[(size_t)(r0 + rr) * N + c] = o;
                    else ((unsigned short*)Cv)[(size_t)(r0 + rr) * N + c] = f2bf(o);
                }
            }
        }
    } else {
        const bool is_off = (col0 < 1024);   // block-uniform (1024 % 128 == 0)
        if (is_off) {
            float* C = (float*)Cv;
#pragma unroll
            for (int ni = 0; ni < 4; ++ni) {
                const int cg = col0 + wc * 64 + ni * 16 + l16;
                // cg = h*128 + l*32 + p*2 + xy
                const int xy = cg & 1, p = (cg >> 1) & 15, l = (cg >> 5) & 3;
                const float lam = (float)p * (1.0f / 15.0f);
                const float l2 = lam * lam, l3 = l2 * lam;
                const float rW = (l == 0) ? 0.015625f : (l == 1) ? 0.03125f
                                : (l == 2) ? 0.0625f : 0.125f;
                const float bv = bias[cg];
#pragma unroll
                for (int mi = 0; mi < 4; ++mi) {
                    const int r0 = row0 + wr * 64 + mi * 16 + quad * 4;
#pragma unroll
                    for (int rr = 0; rr < 4; ++rr) {
                        const int r = r0 + rr;
                        const float4 rp = *(const float4*)(refp + (size_t)r * 8 + xy * 4);
                        const float poly = rp.x * l3 + rp.y * l2 + rp.z * lam + rp.w;
                        C[(size_t)r * 1024 + cg] = poly + (acc[mi][ni][rr] + bv) * rW;
                    }
                }
            }
        } else {
            // fused softmax: this wave holds one head's 64 logits (ni*16+l16)
            // for 64 rows. Reduce over ni (in-reg) x l16 (shfl_xor 1,2,4,8).
            const int cabase = col0 - 1024 + wc * 64;   // multiple of 64
            float bv[4];
#pragma unroll
            for (int ni = 0; ni < 4; ++ni) bv[ni] = bias2[cabase + ni * 16 + l16];
#pragma unroll
            for (int mi = 0; mi < 4; ++mi) {
                const int r0 = row0 + wr * 64 + mi * 16 + quad * 4;
#pragma unroll
                for (int rr = 0; rr < 4; ++rr) {
                    float v0 = acc[mi][0][rr] + bv[0];
                    float v1 = acc[mi][1][rr] + bv[1];
                    float v2 = acc[mi][2][rr] + bv[2];
                    float v3 = acc[mi][3][rr] + bv[3];
                    float mx = fmaxf(fmaxf(v0, v1), fmaxf(v2, v3));
#pragma unroll
                    for (int mk = 1; mk < 16; mk <<= 1) mx = fmaxf(mx, __shfl_xor(mx, mk));
                    v0 = __expf(v0 - mx); v1 = __expf(v1 - mx);
                    v2 = __expf(v2 - mx); v3 = __expf(v3 - mx);
                    float s = v0 + v1 + v2 + v3;
#pragma unroll
                    for (int mk = 1; mk < 16; mk <<= 1) s += __shfl_xor(s, mk);
                    const float inv = 1.0f / s;
                    const size_t rb = (size_t)(r0 + rr) * 512 + cabase + l16;
                    C2[rb]      = v0 * inv;
                    C2[rb + 16] = v1 * inv;
                    C2[rb + 32] = v2 * inv;
                    C2[rb + 48] = v3 * inv;
                }
            }
        }
    }
}

// One launch: v-projection (blocks 0..339) + fused offsets/attn GEMM (340..723).
__global__ __launch_bounds__(256) void gemm_fused(const unsigned short* __restrict__ val_bf,
                                                  const unsigned short* __restrict__ qry_bf,
                                                  const unsigned short* __restrict__ Wt,
                                                  const float* __restrict__ b_value,
                                                  const float* __restrict__ b_off,
                                                  const float* __restrict__ b_attn,
                                                  const float* __restrict__ refp,
                                                  unsigned short* __restrict__ v_proj,
                                                  float* __restrict__ loc_out,
                                                  float* __restrict__ attn_out) {
    const int b = blockIdx.x;
    if (b < 340) {
        gemm_nolds<2>(val_bf, Wt, b_value, nullptr, nullptr,
                      v_proj, nullptr, 256, b & 1, b >> 1);
    } else {
        const int b2 = b - 340;
        gemm_nolds<1>(qry_bf, Wt + (size_t)256 * KDIM, b_off, b_attn, refp,
                      loc_out, attn_out, 1536, b2 % 12, b2 / 12);
    }
}

// out-projection: fp32 out = interm(bf16) @ W_out^T + b_out
__global__ __launch_bounds__(256) void gemm_outp(const unsigned short* __restrict__ interm,
                                                 const unsigned short* __restrict__ Wt_out,
                                                 const float* __restrict__ b_out,
                                                 float* __restrict__ out) {
    gemm_nolds<0>(interm, Wt_out, b_out, nullptr, nullptr,
                  out, nullptr, 256, blockIdx.x & 1, blockIdx.x >> 1);
}

// ---------------- bilinear sampling + attention weighting (bf16 v) ---------------
// 16 lanes per (b,q,h): lane = (lvl 0..3) x (channel-octet 0..3); each lane
// loads 8 bf16 channels (16B) per corner. Scalar point math redundancy = 4x.
// Cross-level reduce via shfl_xor(4,8). ANTI-SPILL (R4 lesson): point loop NOT
// unrolled; launch_bounds(256,4) pins VGPR <= 128. [unchanged from R5]
__global__ __launch_bounds__(256, 4) void sample_kernel(const unsigned short* __restrict__ v,
                                                        const float* __restrict__ loc,
                                                        const float* __restrict__ attn,
                                                        unsigned short* __restrict__ interm) {
    const int t = threadIdx.x;
    const int g = blockIdx.x * 16 + (t >> 4);   // (b*1024+q)*8 + h
    const int l16i = t & 15;
    const int lvl = l16i >> 2;                  // level 0..3
    const int cq  = l16i & 3;                   // channel octet (8 bf16)
    const int h = g & 7, bq = g >> 3, b = bq >> 10;

    const int W = 64 >> lvl;
    const float Wf = (float)W;
    const int sh = 6 - lvl;
    const int start = (lvl == 0) ? 0 : (lvl == 1) ? 4096 : (lvl == 2) ? 5120 : 5376;

    const float* lp = loc  + (size_t)g * 128 + lvl * 32;   // this level's 16 pts
    const float* ap = attn + (size_t)g * 64  + lvl * 16;
    const unsigned short* vl = v + ((size_t)b * LV + start) * EMB + h * HD + cq * 8;

    float acc[8] = {};

    auto cadd = [&](const uint4 q, float wgt) {
        acc[0] = fmaf(wgt, __builtin_bit_cast(float, q.x << 16), acc[0]);
        acc[1] = fmaf(wgt, __builtin_bit_cast(float, q.x & 0xffff0000u), acc[1]);
        acc[2] = fmaf(wgt, __builtin_bit_cast(float, q.y << 16), acc[2]);
        acc[3] = fmaf(wgt, __builtin_bit_cast(float, q.y & 0xffff0000u), acc[3]);
        acc[4] = fmaf(wgt, __builtin_bit_cast(float, q.z << 16), acc[4]);
        acc[5] = fmaf(wgt, __builtin_bit_cast(float, q.z & 0xffff0000u), acc[5]);
        acc[6] = fmaf(wgt, __builtin_bit_cast(float, q.w << 16), acc[6]);
        acc[7] = fmaf(wgt, __builtin_bit_cast(float, q.w & 0xffff0000u), acc[7]);
    };

    auto point = [&](float lx, float ly, float wt) {
        const float x = lx * Wf - 0.5f, y = ly * Wf - 0.5f;
        const float x0f = floorf(x), y0f = floorf(y);
        const float wx = x - x0f, wy = y - y0f;
        const int x0 = (int)x0f, y0 = (int)y0f;
        const int x1 = x0 + 1, y1 = y0 + 1;
        const float iwx = 1.f - wx, iwy = 1.f - wy;
        float w00 = iwx * iwy * wt, w10 = wx * iwy * wt;
        float w01 = iwx * wy * wt,  w11 = wx * wy * wt;
        const bool vx0 = (unsigned)x0 < (unsigned)W;
        const bool vx1 = (unsigned)x1 < (unsigned)W;
        const bool vy0 = (unsigned)y0 < (unsigned)W;
        const bool vy1 = (unsigned)y1 < (unsigned)W;
        w00 = (vx0 & vy0) ? w00 : 0.f;
        w10 = (vx1 & vy0) ? w10 : 0.f;
        w01 = (vx0 & vy1) ? w01 : 0.f;
        w11 = (vx1 & vy1) ? w11 : 0.f;
        const int cx0 = min(max(x0, 0), W - 1);
        const int cx1 = min(max(x1, 0), W - 1);
        const int cy0 = min(max(y0, 0), W - 1);
        const int cy1 = min(max(y1, 0), W - 1);
        const uint4 g00 = *(const uint4*)(vl + (size_t)((cy0 << sh) + cx0) * EMB);
        const uint4 g10 = *(const uint4*)(vl + (size_t)((cy0 << sh) + cx1) * EMB);
        const uint4 g01 = *(const uint4*)(vl + (size_t)((cy1 << sh) + cx0) * EMB);
        const uint4 g11 = *(const uint4*)(vl + (size_t)((cy1 << sh) + cx1) * EMB);
        cadd(g00, w00); cadd(g10, w10); cadd(g01, w01); cadd(g11, w11);
    };

#pragma unroll 1
    for (int p4 = 0; p4 < 16; p4 += 4) {
        const float4 la = *(const float4*)(lp + 2 * p4);
        const float4 lb = *(const float4*)(lp + 2 * p4 + 4);
        const float4 wv = *(const float4*)(ap + p4);
        point(la.x, la.y, wv.x); point(la.z, la.w, wv.y);
        point(lb.x, lb.y, wv.z); point(lb.z, lb.w, wv.w);
    }

    // reduce across the 4 level-quads (lane bits 2,3)
#pragma unroll
    for (int m = 4; m <= 8; m <<= 1)
#pragma unroll
        for (int k = 0; k < 8; ++k) acc[k] += __shfl_xor(acc[k], m);

    if (lvl == 0) {
        unsigned short o[8];
#pragma unroll
        for (int k = 0; k < 8; ++k) o[k] = f2bf(acc[k]);
        *(uint4*)(interm + (size_t)bq * EMB + h * HD + cq * 8) = *(const uint4*)o;
    }
}

// ---------------- host launch ----------------------------------------------------
extern "C" void kernel_launch(void* const* d_in, const int* in_sizes, int n_in,
                              void* d_out, int out_size, void* d_ws, size_t ws_size,
                              hipStream_t stream) {
    const float* query   = (const float*)d_in[0];
    const float* refp    = (const float*)d_in[1];
    const float* value   = (const float*)d_in[2];
    const float* W_value = (const float*)d_in[3];
    const float* b_value = (const float*)d_in[4];
    const float* W_off   = (const float*)d_in[5];
    const float* b_off   = (const float*)d_in[6];
    const float* W_attn  = (const float*)d_in[7];
    const float* b_attn  = (const float*)d_in[8];
    const float* W_out   = (const float*)d_in[9];
    const float* b_out   = (const float*)d_in[10];

    float* out      = (float*)d_out;            // [4,1024,256]
    float* loc_out  = out + 1048576;            // [4,1024,8,4,16,2]
    float* attn_out = out + 5242880;            // [4,1024,8,4,16]

    // workspace layout (25,427,968 B — same footprint R2 proved):
    //   [0, 11141120)          val_bf (launches 1-2)  ALIASED WITH interm (3-4)
    //   [11141120, 22282240)   v_proj bf16
    //   [22282240, 24379392)   qry_bf
    //   [24379392, 25427968)   Wt_all
    char* ws = (char*)d_ws;
    unsigned short* val_bf = (unsigned short*)ws;
    unsigned short* interm = (unsigned short*)ws;                 // alias, see above
    unsigned short* v_proj = (unsigned short*)(ws + 11141120);
    unsigned short* qry_bf = (unsigned short*)(ws + 22282240);
    unsigned short* Wt_all = (unsigned short*)(ws + 24379392);

    const dim3 blk(256);

    // weights transpose+convert (512 blocks) + value/query fp32->bf16 (3232 blocks)
    prep<<<3744, blk, 0, stream>>>(W_value, W_off, W_attn, W_out, value, query,
                                   Wt_all, val_bf, qry_bf);

    // v-projection (340 blocks) + fused offsets/attn GEMM w/ loc-poly + softmax (384)
    gemm_fused<<<724, blk, 0, stream>>>(val_bf, qry_bf, Wt_all, b_value, b_off,
                                        b_attn, refp, v_proj, loc_out, attn_out);

    // bilinear gather + attention weighting (bf16 v) -> interm (overwrites val_bf)
    sample_kernel<<<(BS * LQ * NH) / 16, blk, 0, stream>>>(v_proj, loc_out, attn_out, interm);

    // output = interm @ W_out^T + b_out
    gemm_outp<<<64, blk, 0, stream>>>(interm, Wt_all + (size_t)1792 * KDIM, b_out, out);
}

// Round 7
// 165.599 us; speedup vs baseline: 1.1074x; 1.1074x over previous
//
#include <hip/hip_runtime.h>
#include <math.h>

// Problem constants
#define BS 4
#define LQ 1024
#define EMB 256
#define NH 8
#define NL 4
#define NP 16
#define HD 32
#define LV 5440     // 64*64 + 32*32 + 16*16 + 8*8
#define LVP 5936    // padded: 66^2 + 34^2 + 18^2 + 10^2
#define KDIM 256    // all GEMMs have K = 256

typedef __attribute__((ext_vector_type(8))) short short8;  // 8 bf16 = 4 VGPRs
typedef __attribute__((ext_vector_type(4))) float f32x4;

__device__ inline unsigned short f2bf(float f) {
    unsigned u = __builtin_bit_cast(unsigned, f);
    u += 0x7fff + ((u >> 16) & 1);   // round-to-nearest-even
    return (unsigned short)(u >> 16);
}

// Fragment-major layout for a row-major [R][256] bf16 matrix:
//   tile t = (r>>4)*8 + (k>>5)   (16 rows x 32 k per tile, 512 elems = 1KB)
//   slot  = (r&15) + 16*((k>>3)&3)    == MFMA lane id
//   elem  = k & 7
//   offset = t*512 + slot*8 + elem
// A wave's 16x16x32 fragment load is then ONE contiguous 1KB burst:
// global_load_dwordx4 at tile_base + lane*16B.  (R6 lesson: row-strided
// fragment loads = 16 scattered 64B txns per instruction.)

// ---------------- prep ------------------------------------------------------------
// blocks [0,512):        weights [K=256][N] fp32 -> Wt fragment-major bf16 rows:
//                        0..255 W_value | 256..1279 W_off | 1280..1791 W_attn | 1792..2047 W_out
// blocks [512,3232):     value fp32 -> val_bf fragment-major (21760 rows)
// blocks [3232,3744):    query fp32 -> qry_bf fragment-major (4096 rows)
// blocks [3744,3992):    zero the 1-pixel borders of padded v_proj
__global__ __launch_bounds__(256) void prep(const float* __restrict__ Wv,
                                            const float* __restrict__ Wo,
                                            const float* __restrict__ Wa,
                                            const float* __restrict__ Wu,
                                            const float* __restrict__ value,
                                            const float* __restrict__ query,
                                            unsigned short* __restrict__ Wt,
                                            unsigned short* __restrict__ val_bf,
                                            unsigned short* __restrict__ qry_bf,
                                            unsigned short* __restrict__ v_pad) {
    const int blk = blockIdx.x;
    const int t = threadIdx.x;
    if (blk < 512) {
        __shared__ float tile[32][33];     // [k_local][n_local]
        const int n0 = (blk & 63) * 32, k0 = (blk >> 6) * 32;
        const float* src; int N, nloc;
        if (n0 < 256)       { src = Wv; N = 256;  nloc = n0; }
        else if (n0 < 1280) { src = Wo; N = 1024; nloc = n0 - 256; }
        else if (n0 < 1792) { src = Wa; N = 512;  nloc = n0 - 1280; }
        else                { src = Wu; N = 256;  nloc = n0 - 1792; }
        const int tx = t & 31, ty = t >> 5;  // ty 0..7
#pragma unroll
        for (int i = 0; i < 32; i += 8)
            tile[ty + i][tx] = src[(size_t)(k0 + ty + i) * N + nloc + tx];
        __syncthreads();
        if (t < 128) {                       // 32 n x 4 k-octets
            const int n_loc = t & 31, oct = t >> 5;
            const int n = n0 + n_loc;
            short8 h;
#pragma unroll
            for (int e = 0; e < 8; ++e) h[e] = (short)f2bf(tile[oct * 8 + e][n_loc]);
            const size_t off = ((size_t)(n >> 4) * 8 + (k0 >> 5)) * 512
                             + ((n & 15) + 16 * oct) * 8;
            *(short8*)(Wt + off) = h;
        }
    } else if (blk < 3744) {
        // fragment-major fp32->bf16: thread = (row, k-octet)
        int i; const float* src; unsigned short* dst;
        if (blk < 3232) { i = (blk - 512) * 256 + t;  src = value; dst = val_bf; }
        else            { i = (blk - 3232) * 256 + t; src = query; dst = qry_bf; }
        const int r = i >> 5, oct = i & 31, k0 = oct * 8;
        const float4 f0 = *(const float4*)(src + (size_t)r * KDIM + k0);
        const float4 f1 = *(const float4*)(src + (size_t)r * KDIM + k0 + 4);
        short8 h;
        h[0] = (short)f2bf(f0.x); h[1] = (short)f2bf(f0.y);
        h[2] = (short)f2bf(f0.z); h[3] = (short)f2bf(f0.w);
        h[4] = (short)f2bf(f1.x); h[5] = (short)f2bf(f1.y);
        h[6] = (short)f2bf(f1.z); h[7] = (short)f2bf(f1.w);
        const size_t off = ((size_t)(r >> 4) * 8 + (oct >> 2)) * 512
                         + ((r & 15) + 16 * (oct & 3)) * 8;
        *(short8*)(dst + off) = h;
    } else {
        // zero border pixels of padded v (4 batches x 496 border pixels, 512B each)
        const int pidx = (blk - 3744) * 8 + (t >> 5);   // 0..1983
        const int lane32 = t & 31;
        const unsigned b = (unsigned)pidx / 496u;
        const unsigned rem = (unsigned)pidx - b * 496u;
        int Wd, W2, pb, i;
        if (rem < 260)      { Wd = 64; W2 = 66; pb = 0;    i = rem; }
        else if (rem < 392) { Wd = 32; W2 = 34; pb = 4356; i = rem - 260; }
        else if (rem < 460) { Wd = 16; W2 = 18; pb = 5512; i = rem - 392; }
        else                { Wd = 8;  W2 = 10; pb = 5836; i = rem - 460; }
        int y, x;
        if (i < W2)          { y = 0;      x = i; }
        else if (i < 2 * W2) { y = Wd + 1; x = i - W2; }
        else { const int j = i - 2 * W2; y = 1 + (j >> 1); x = (j & 1) ? (Wd + 1) : 0; }
        const size_t off = ((size_t)b * LVP + pb + y * W2 + x) * EMB + lane32 * 8;
        uint4 z = {0, 0, 0, 0};
        *(uint4*)(v_pad + off) = z;
    }
}

// ---------------- barrier-free no-LDS bf16 MFMA GEMM, 128x128 tile ---------------
// 4 waves in 2x2; each wave computes 64x64 via 4x4 frags of 16x16x32.
// Fragment-major operands: each fragment load = one contiguous 1KB wave burst.
// MODE 1: fused qkv epilogue (N=1536): cols <1024 -> sampling locations with
//         reference-point polynomial; cols >=1024 -> attn logits with fused
//         softmax over each (row, head)'s 64 logits -> fp32 C2.
// MODE 2: bf16 v-projection written into the PADDED v layout (row -> b,lvl,y,x).
// MODE 0: fp32 row-major C = acc + bias[c]
template <int MODE>
__device__ __forceinline__ void gemm_nolds(const unsigned short* __restrict__ A,
                                           const unsigned short* __restrict__ Bt,
                                           const float* __restrict__ bias,
                                           const float* __restrict__ bias2,
                                           const float* __restrict__ refp,
                                           void* __restrict__ Cv,
                                           float* __restrict__ C2,
                                           int N, int bx, int by) {
    const int t = threadIdx.x;
    const int lane = t & 63, w = t >> 6;
    const int quad = lane >> 4, l16 = lane & 15;
    const int wr = w >> 1, wc = w & 1;
    const int row0 = by * 128, col0 = bx * 128;

    const unsigned short* ap = A  + ((size_t)((row0 >> 4) + wr * 4) * 8) * 512 + lane * 8;
    const unsigned short* bp = Bt + ((size_t)((col0 >> 4) + wc * 4) * 8) * 512 + lane * 8;

    f32x4 acc[4][4] = {};

#pragma unroll 2
    for (int kt = 0; kt < 8; ++kt) {
        short8 af[4], bf[4];
#pragma unroll
        for (int mi = 0; mi < 4; ++mi)
            af[mi] = *(const short8*)(ap + (size_t)mi * 4096 + kt * 512);
#pragma unroll
        for (int ni = 0; ni < 4; ++ni)
            bf[ni] = *(const short8*)(bp + (size_t)ni * 4096 + kt * 512);
#pragma unroll
        for (int mi = 0; mi < 4; ++mi)
#pragma unroll
            for (int ni = 0; ni < 4; ++ni)
                acc[mi][ni] = __builtin_amdgcn_mfma_f32_16x16x32_bf16(af[mi], bf[ni],
                                                                      acc[mi][ni], 0, 0, 0);
    }

    // C/D layout: col = lane&15, row = quad*4 + reg  [m89-verified, R2-R6 verified]
    if (MODE == 0) {
#pragma unroll
        for (int ni = 0; ni < 4; ++ni) {
            const int c = col0 + wc * 64 + ni * 16 + l16;
            const float bv = bias[c];
#pragma unroll
            for (int mi = 0; mi < 4; ++mi) {
                const int r0 = row0 + wr * 64 + mi * 16 + quad * 4;
#pragma unroll
                for (int rr = 0; rr < 4; ++rr)
                    ((float*)Cv)[(size_t)(r0 + rr) * N + c] = acc[mi][ni][rr] + bv;
            }
        }
    } else if (MODE == 2) {
        // v-projection into padded layout
        unsigned short* C = (unsigned short*)Cv;
        float bv[4];
        int cc[4];
#pragma unroll
        for (int ni = 0; ni < 4; ++ni) {
            cc[ni] = col0 + wc * 64 + ni * 16 + l16;
            bv[ni] = bias[cc[ni]];
        }
#pragma unroll
        for (int mi = 0; mi < 4; ++mi) {
#pragma unroll
            for (int rr = 0; rr < 4; ++rr) {
                const unsigned r = row0 + wr * 64 + mi * 16 + quad * 4 + rr;
                const unsigned b = r / 5440u;
                const unsigned flat = r - b * 5440u;
                unsigned y, x, W2, pb;
                if (flat < 4096)      { y = flat >> 6; x = flat & 63; W2 = 66; pb = 0; }
                else if (flat < 5120) { const unsigned f = flat - 4096; y = f >> 5; x = f & 31; W2 = 34; pb = 4356; }
                else if (flat < 5376) { const unsigned f = flat - 5120; y = f >> 4; x = f & 15; W2 = 18; pb = 5512; }
                else                  { const unsigned f = flat - 5376; y = f >> 3; x = f & 7;  W2 = 10; pb = 5836; }
                const size_t rowbase = ((size_t)b * LVP + pb + (y + 1) * W2 + (x + 1)) * EMB;
#pragma unroll
                for (int ni = 0; ni < 4; ++ni)
                    C[rowbase + cc[ni]] = f2bf(acc[mi][ni][rr] + bv[ni]);
            }
        }
    } else {
        const bool is_off = (col0 < 1024);   // block-uniform (1024 % 128 == 0)
        if (is_off) {
            float* C = (float*)Cv;
#pragma unroll
            for (int ni = 0; ni < 4; ++ni) {
                const int cg = col0 + wc * 64 + ni * 16 + l16;
                // cg = h*128 + l*32 + p*2 + xy
                const int xy = cg & 1, p = (cg >> 1) & 15, l = (cg >> 5) & 3;
                const float lam = (float)p * (1.0f / 15.0f);
                const float l2 = lam * lam, l3 = l2 * lam;
                const float rW = (l == 0) ? 0.015625f : (l == 1) ? 0.03125f
                                : (l == 2) ? 0.0625f : 0.125f;
                const float bv = bias[cg];
#pragma unroll
                for (int mi = 0; mi < 4; ++mi) {
                    const int r0 = row0 + wr * 64 + mi * 16 + quad * 4;
#pragma unroll
                    for (int rr = 0; rr < 4; ++rr) {
                        const int r = r0 + rr;
                        const float4 rp = *(const float4*)(refp + (size_t)r * 8 + xy * 4);
                        const float poly = rp.x * l3 + rp.y * l2 + rp.z * lam + rp.w;
                        C[(size_t)r * 1024 + cg] = poly + (acc[mi][ni][rr] + bv) * rW;
                    }
                }
            }
        } else {
            // fused softmax: this wave holds one head's 64 logits (ni*16+l16)
            // for 64 rows. Reduce over ni (in-reg) x l16 (shfl_xor 1,2,4,8).
            const int cabase = col0 - 1024 + wc * 64;   // multiple of 64
            float bv[4];
#pragma unroll
            for (int ni = 0; ni < 4; ++ni) bv[ni] = bias2[cabase + ni * 16 + l16];
#pragma unroll
            for (int mi = 0; mi < 4; ++mi) {
                const int r0 = row0 + wr * 64 + mi * 16 + quad * 4;
#pragma unroll
                for (int rr = 0; rr < 4; ++rr) {
                    float v0 = acc[mi][0][rr] + bv[0];
                    float v1 = acc[mi][1][rr] + bv[1];
                    float v2 = acc[mi][2][rr] + bv[2];
                    float v3 = acc[mi][3][rr] + bv[3];
                    float mx = fmaxf(fmaxf(v0, v1), fmaxf(v2, v3));
#pragma unroll
                    for (int mk = 1; mk < 16; mk <<= 1) mx = fmaxf(mx, __shfl_xor(mx, mk));
                    v0 = __expf(v0 - mx); v1 = __expf(v1 - mx);
                    v2 = __expf(v2 - mx); v3 = __expf(v3 - mx);
                    float s = v0 + v1 + v2 + v3;
#pragma unroll
                    for (int mk = 1; mk < 16; mk <<= 1) s += __shfl_xor(s, mk);
                    const float inv = 1.0f / s;
                    const size_t rb = (size_t)(r0 + rr) * 512 + cabase + l16;
                    C2[rb]      = v0 * inv;
                    C2[rb + 16] = v1 * inv;
                    C2[rb + 32] = v2 * inv;
                    C2[rb + 48] = v3 * inv;
                }
            }
        }
    }
}

// One launch: v-projection (blocks 0..339) + fused offsets/attn GEMM (340..723).
__global__ __launch_bounds__(256, 2) void gemm_fused(const unsigned short* __restrict__ val_bf,
                                                     const unsigned short* __restrict__ qry_bf,
                                                     const unsigned short* __restrict__ Wt,
                                                     const float* __restrict__ b_value,
                                                     const float* __restrict__ b_off,
                                                     const float* __restrict__ b_attn,
                                                     const float* __restrict__ refp,
                                                     unsigned short* __restrict__ v_pad,
                                                     float* __restrict__ loc_out,
                                                     float* __restrict__ attn_out) {
    const int b = blockIdx.x;
    if (b < 340) {
        gemm_nolds<2>(val_bf, Wt, b_value, nullptr, nullptr,
                      v_pad, nullptr, 256, b & 1, b >> 1);
    } else {
        const int b2 = b - 340;
        gemm_nolds<1>(qry_bf, Wt + (size_t)256 * KDIM, b_off, b_attn, refp,
                      loc_out, attn_out, 1536, b2 % 12, b2 / 12);
    }
}

// out-projection: fp32 out = interm(bf16, fragment-major) @ W_out^T + b_out
__global__ __launch_bounds__(256, 2) void gemm_outp(const unsigned short* __restrict__ interm,
                                                    const unsigned short* __restrict__ Wt_out,
                                                    const float* __restrict__ b_out,
                                                    float* __restrict__ out) {
    gemm_nolds<0>(interm, Wt_out, b_out, nullptr, nullptr,
                  out, nullptr, 256, blockIdx.x & 1, blockIdx.x >> 1);
}

// ---------------- bilinear sampling + attention weighting (padded bf16 v) --------
// 16 lanes per (b,q,h): lane = (lvl 0..3) x (channel-octet 0..3); each lane
// loads 8 bf16 channels (16B) per corner. Zero-padded border (1 pixel) removes
// ALL valid-masks and clamps: coords clamped to [-1, W] land on zero pixels
// with the exact reference zero-padding semantics. The 4 corners are base,
// +256, +rowpitch, +rowpitch+256 elems. Cross-level reduce via shfl_xor(4,8).
// ANTI-SPILL (R4 lesson): point loop NOT unrolled; launch_bounds caps VGPR 128.
__global__ __launch_bounds__(256, 4) void sample_kernel(const unsigned short* __restrict__ v,
                                                        const float* __restrict__ loc,
                                                        const float* __restrict__ attn,
                                                        unsigned short* __restrict__ interm) {
    const int t = threadIdx.x;
    const int g = blockIdx.x * 16 + (t >> 4);   // (b*1024+q)*8 + h
    const int l16i = t & 15;
    const int lvl = l16i >> 2;                  // level 0..3
    const int cq  = l16i & 3;                   // channel octet (8 bf16)
    const int h = g & 7, bq = g >> 3, b = bq >> 10;

    const int Wd = 64 >> lvl;
    const float Wf = (float)Wd;
    const int W2 = Wd + 2;
    const int rowoff = W2 * EMB;
    const int pb = (lvl == 0) ? 0 : (lvl == 1) ? 4356 : (lvl == 2) ? 5512 : 5836;

    const float* lp = loc  + (size_t)g * 128 + lvl * 32;   // this level's 16 pts
    const float* ap = attn + (size_t)g * 64  + lvl * 16;
    const unsigned short* vl = v + ((size_t)b * LVP + pb) * EMB + h * HD + cq * 8;

    float2 acc2[4] = {};

    auto cvt2 = [](unsigned d) {
        uint2 u; u.x = d << 16; u.y = d & 0xffff0000u;
        return __builtin_bit_cast(float2, u);
    };
    auto cadd = [&](const uint4 q, float wgt) {
        const float2 w2 = make_float2(wgt, wgt);
        acc2[0] += cvt2(q.x) * w2;
        acc2[1] += cvt2(q.y) * w2;
        acc2[2] += cvt2(q.z) * w2;
        acc2[3] += cvt2(q.w) * w2;
    };

    auto point = [&](float lx, float ly, float wt) {
        const float x = fmaf(lx, Wf, -0.5f);
        const float y = fmaf(ly, Wf, -0.5f);
        const float xc = fminf(fmaxf(x, -1.0f), Wf);
        const float yc = fminf(fmaxf(y, -1.0f), Wf);
        const float x0f = fminf(floorf(xc), Wf - 1.0f);
        const float y0f = fminf(floorf(yc), Wf - 1.0f);
        const float wx = xc - x0f, wy = yc - y0f;
        const float iwx = 1.0f - wx, iwy = 1.0f - wy;
        const int px = (int)x0f + 1;          // [0, W]
        const int py = (int)y0f + 1;          // [0, W]
        const int base = (py * W2 + px) * EMB;
        const float w00 = iwx * iwy * wt, w10 = wx * iwy * wt;
        const float w01 = iwx * wy * wt,  w11 = wx * wy * wt;
        const uint4 g00 = *(const uint4*)(vl + base);
        const uint4 g10 = *(const uint4*)(vl + base + EMB);
        const uint4 g01 = *(const uint4*)(vl + base + rowoff);
        const uint4 g11 = *(const uint4*)(vl + base + rowoff + EMB);
        cadd(g00, w00); cadd(g10, w10); cadd(g01, w01); cadd(g11, w11);
    };

#pragma unroll 1
    for (int p4 = 0; p4 < 16; p4 += 4) {
        const float4 la = *(const float4*)(lp + 2 * p4);
        const float4 lb = *(const float4*)(lp + 2 * p4 + 4);
        const float4 wv = *(const float4*)(ap + p4);
        point(la.x, la.y, wv.x); point(la.z, la.w, wv.y);
        point(lb.x, lb.y, wv.z); point(lb.z, lb.w, wv.w);
    }

    float a[8] = {acc2[0].x, acc2[0].y, acc2[1].x, acc2[1].y,
                  acc2[2].x, acc2[2].y, acc2[3].x, acc2[3].y};
    // reduce across the 4 level-quads (lane bits 2,3)
#pragma unroll
    for (int m = 4; m <= 8; m <<= 1)
#pragma unroll
        for (int k = 0; k < 8; ++k) a[k] += __shfl_xor(a[k], m);

    if (lvl == 0) {
        unsigned short o[8];
#pragma unroll
        for (int k = 0; k < 8; ++k) o[k] = f2bf(a[k]);
        // fragment-major interm: row = bq, k = h*32 + cq*8
        const size_t off = ((size_t)(bq >> 4) * 8 + h) * 512
                         + ((bq & 15) + 16 * cq) * 8;
        *(uint4*)(interm + off) = *(const uint4*)o;
    }
}

// ---------------- host launch ----------------------------------------------------
extern "C" void kernel_launch(void* const* d_in, const int* in_sizes, int n_in,
                              void* d_out, int out_size, void* d_ws, size_t ws_size,
                              hipStream_t stream) {
    const float* query   = (const float*)d_in[0];
    const float* refp    = (const float*)d_in[1];
    const float* value   = (const float*)d_in[2];
    const float* W_value = (const float*)d_in[3];
    const float* b_value = (const float*)d_in[4];
    const float* W_off   = (const float*)d_in[5];
    const float* b_off   = (const float*)d_in[6];
    const float* W_attn  = (const float*)d_in[7];
    const float* b_attn  = (const float*)d_in[8];
    const float* W_out   = (const float*)d_in[9];
    const float* b_out   = (const float*)d_in[10];

    float* out      = (float*)d_out;            // [4,1024,256]
    float* loc_out  = out + 1048576;            // [4,1024,8,4,16,2]
    float* attn_out = out + 5242880;            // [4,1024,8,4,16]

    // workspace layout (26,443,776 B <= 26,476,544 B that R1 proved exists):
    //   [0, 12156928)           v_pad   (padded bf16 v-projection)
    //   [12156928, 23298048)    val_bf  (launches 1-2)  ALIASED WITH interm (3-4)
    //   [23298048, 25395200)    qry_bf
    //   [25395200, 26443776)    Wt (fragment-major, 2048 rows x 256)
    char* ws = (char*)d_ws;
    unsigned short* v_pad  = (unsigned short*)ws;
    unsigned short* val_bf = (unsigned short*)(ws + 12156928);
    unsigned short* interm = (unsigned short*)(ws + 12156928);    // alias
    unsigned short* qry_bf = (unsigned short*)(ws + 23298048);
    unsigned short* Wt_all = (unsigned short*)(ws + 25395200);

    const dim3 blk(256);

    // weights -> fragment-major bf16; value/query -> fragment-major bf16; pad borders
    prep<<<3992, blk, 0, stream>>>(W_value, W_off, W_attn, W_out, value, query,
                                   Wt_all, val_bf, qry_bf, v_pad);

    // v-projection into padded layout (340 blocks) + fused offsets/attn GEMM (384)
    gemm_fused<<<724, blk, 0, stream>>>(val_bf, qry_bf, Wt_all, b_value, b_off,
                                        b_attn, refp, v_pad, loc_out, attn_out);

    // bilinear gather + attention weighting -> interm (fragment-major, overwrites val_bf)
    sample_kernel<<<(BS * LQ * NH) / 16, blk, 0, stream>>>(v_pad, loc_out, attn_out, interm);

    // output = interm @ W_out^T + b_out
    gemm_outp<<<64, blk, 0, stream>>>(interm, Wt_all + (size_t)1792 * KDIM, b_out, out);
}